// Round 1
// 406.914 us; speedup vs baseline: 1.1811x; 1.1811x over previous
//
#include <hip/hip_runtime.h>
#include <cstdint>
#include <cstddef>

#define B_   16
#define L_   2048
#define H_   1024
#define S_   32
#define P_   256
#define NASP 8
#define NRAT 5
#define M_   (B_*L_)   /* 32768 */
#define N_   (2*P_)    /* 512  */

typedef unsigned short u16;
typedef __bf16 bf16;
typedef u16  u16x4  __attribute__((ext_vector_type(4)));
typedef u16  u16x8  __attribute__((ext_vector_type(8)));
typedef bf16 bf16x8 __attribute__((ext_vector_type(8)));
typedef float f32x4 __attribute__((ext_vector_type(4)));

// f32 -> bf16 bits (round-to-nearest-even), bf16 bits -> f32.
__device__ __forceinline__ u16 f2b(float f){
  unsigned int u = __float_as_uint(f);
  u += 0x7FFFu + ((u >> 16) & 1u);
  return (u16)(u >> 16);
}
__device__ __forceinline__ float b2f(u16 v){
  return __uint_as_float(((unsigned int)v) << 16);
}

// ---------------------------------------------------------------- utilities
__device__ __forceinline__ float2 block_reduce2(float a, float b){
  __shared__ float sh[8];
  #pragma unroll
  for (int o = 32; o > 0; o >>= 1){
    a += __shfl_down(a, o, 64);
    b += __shfl_down(b, o, 64);
  }
  int w = threadIdx.x >> 6;
  if ((threadIdx.x & 63) == 0){ sh[w] = a; sh[w + 4] = b; }
  __syncthreads();
  float2 r;
  r.x = sh[0] + sh[1] + sh[2] + sh[3];
  r.y = sh[4] + sh[5] + sh[6] + sh[7];
  __syncthreads();
  return r;
}

// ------------------------------------------------- K0a: fold LN into weights
__global__ void fold_k(const float* __restrict__ Wa, const float* __restrict__ Ws,
                       const float* __restrict__ sa, const float* __restrict__ ba,
                       const float* __restrict__ ss, const float* __restrict__ bs,
                       u16* __restrict__ WcT, float* __restrict__ biasc){
  int n = blockIdx.x;                 // 0..511
  const float* W; const float* sc; const float* bi; int col;
  if (n < P_){ W = Wa; sc = sa; bi = ba; col = n; }
  else       { W = Ws; sc = ss; bi = bs; col = n - P_; }
  float bacc = 0.f;
  #pragma unroll
  for (int i = 0; i < 4; ++i){
    int k = threadIdx.x + i * 256;
    float w = W[(size_t)k * P_ + col];
    WcT[(size_t)n * H_ + k] = f2b(w * sc[k]);
    bacc += w * bi[k];
  }
  float2 r = block_reduce2(bacc, 0.f);
  if (threadIdx.x == 0) biasc[n] = r.x;
}

// --------------------------------------------- K0b: sentence marker indices
__global__ void markers_k(const int* __restrict__ p_index, int* __restrict__ pi){
  int b = blockIdx.x;
  int lane = threadIdx.x;             // 64 threads = 1 wave
  int cnt = 0;
  for (int c = 0; c < L_ / 64; ++c){
    int pos = c * 64 + lane;
    bool f = p_index[(size_t)b * L_ + pos] > 0;
    unsigned long long m = __ballot(f);
    int before = __popcll(m & ((1ull << lane) - 1ull));
    if (f){
      int idx = cnt + before;
      if (idx < S_) pi[b * S_ + idx] = pos;
    }
    cnt += __popcll(m);
  }
}

// -------------------- K1: fused per-row LN stats + normalize -> bf16 xhat
__global__ void stats_xhat_k(const float* __restrict__ x, u16* __restrict__ xhat){
  int row = blockIdx.x;
  int t = threadIdx.x;
  float4 v = ((const float4*)(x + (size_t)row * H_))[t];
  float s  = v.x + v.y + v.z + v.w;
  float ss = v.x*v.x + v.y*v.y + v.z*v.z + v.w*v.w;
  float2 r = block_reduce2(s, ss);
  float mean = r.x * (1.f / H_);
  float var  = fmaxf(r.y * (1.f / H_) - mean * mean, 0.f);
  float rstd = rsqrtf(var + 1e-5f);
  u16x4 o;
  o[0] = f2b((v.x - mean) * rstd);
  o[1] = f2b((v.y - mean) * rstd);
  o[2] = f2b((v.z - mean) * rstd);
  o[3] = f2b((v.w - mean) * rstd);
  ((u16x4*)(xhat + (size_t)row * H_))[t] = o;
}

// --------------------------- K2: GEMM (bf16 A from xhat) + bias + GELU
// proj[m][n] = gelu( xhat[m][:] @ WcT[n][:] + biasc[n] ), bf16 out.
// XCD swizzle: linear l -> xcd = l&7; the 8 n-blocks of one m-tile share an
// XCD (same l mod 8) and are temporally adjacent -> A-tile L2-resident.
__global__ __launch_bounds__(256) void gemm_k(const u16* __restrict__ xhat,
                                              const u16* __restrict__ WcT,
                                              const float* __restrict__ biasc,
                                              u16* __restrict__ proj){
  __shared__ __align__(16) u16 As[128][40];   // pad: 80B row = 5x16B (odd mod 8)
  __shared__ __align__(16) u16 Bs[64][40];
  int t = threadIdx.x;
  unsigned int l = blockIdx.x;          // 0..2047
  unsigned int xcd  = l & 7;
  unsigned int slot = l >> 3;
  unsigned int ntile = slot & 7;
  unsigned int mtile = xcd * 32 + (slot >> 3);
  int nbase = ntile * 64;
  int mbase = mtile * 128;

  // A staging: 128 rows x 4 chunks(16B); 2 per thread (rows t>>2 and +64)
  int rowA = t >> 2, chA = t & 3;
  const u16* arow0 = xhat + (size_t)(mbase + rowA) * H_;
  const u16* arow1 = xhat + (size_t)(mbase + rowA + 64) * H_;
  // B staging: 64 rows x 4 chunks(16B); 1 per thread
  int nB = t >> 2, chB = t & 3;
  const u16* wrow = WcT + (size_t)(nbase + nB) * H_;

  f32x4 acc[2][4] = {};
  int w = t >> 6, lane = t & 63, quad = lane >> 4, l15 = lane & 15;

  for (int kk = 0; kk < H_; kk += 32){
    __syncthreads();
    *reinterpret_cast<u16x8*>(&As[rowA][chA * 8]) =
        *reinterpret_cast<const u16x8*>(arow0 + kk + chA * 8);
    *reinterpret_cast<u16x8*>(&As[rowA + 64][chA * 8]) =
        *reinterpret_cast<const u16x8*>(arow1 + kk + chA * 8);
    *reinterpret_cast<u16x8*>(&Bs[nB][chB * 8]) =
        *reinterpret_cast<const u16x8*>(wrow + kk + chB * 8);
    __syncthreads();

    bf16x8 af0 = *reinterpret_cast<const bf16x8*>(&As[w * 32 + l15][quad * 8]);
    bf16x8 af1 = *reinterpret_cast<const bf16x8*>(&As[w * 32 + 16 + l15][quad * 8]);
    #pragma unroll
    for (int in = 0; in < 4; ++in){
      bf16x8 bf = *reinterpret_cast<const bf16x8*>(&Bs[in * 16 + l15][quad * 8]);
      acc[0][in] = __builtin_amdgcn_mfma_f32_16x16x32_bf16(af0, bf, acc[0][in], 0, 0, 0);
      acc[1][in] = __builtin_amdgcn_mfma_f32_16x16x32_bf16(af1, bf, acc[1][in], 0, 0, 0);
    }
  }

  // epilogue: bias + exact gelu + bf16 store
  #pragma unroll
  for (int in = 0; in < 4; ++in){
    int col = nbase + in * 16 + l15;
    float bv = biasc[col];
    #pragma unroll
    for (int im = 0; im < 2; ++im){
      #pragma unroll
      for (int r = 0; r < 4; ++r){
        int rowg = mbase + w * 32 + im * 16 + quad * 4 + r;
        float vv = acc[im][in][r] + bv;
        float g = 0.5f * vv * (1.0f + erff(vv * 0.70710678118654752f));
        proj[(size_t)rowg * N_ + col] = f2b(g);
      }
    }
  }
}

// ------------------------------------------------- K3: segment (span) means
// Rewritten for parallelism: 1024 threads = 16 waves per block; each wave
// reads one FULL 1KB row (64 lanes x 16B), 16 rows in flight per iteration.
// 512 blocks x 1024 thr = exactly 2 blocks/CU = 32 waves/CU (100% occ cap).
// Cross-wave reduction through 32KB LDS (readers contiguous -> conflict-free).
__global__ __launch_bounds__(1024) void segmean_k(const u16* __restrict__ proj,
                                                  const int* __restrict__ pi,
                                                  float* __restrict__ sent){
  int b = blockIdx.x, j = blockIdx.y;
  int t = threadIdx.x;
  int rg   = t >> 6;        // 0..15 (wave id = row group)
  int lane = t & 63;        // lane covers cols [lane*8, lane*8+8)
  int end   = pi[b * S_ + j];
  int start = (j == 0) ? 0 : (pi[b * S_ + j - 1] + 1);
  end   = min(max(end, 0), L_);
  start = min(max(start, 0), end);
  int cnt = max(end - start, 1);
  float inv = 1.0f / (float)cnt;

  float s[8] = {};
  const u16* base = proj + ((size_t)b * L_ + start) * N_ + lane * 8;
  for (int r = rg; r < cnt; r += 16){
    u16x8 v = *reinterpret_cast<const u16x8*>(base + (size_t)r * N_);
    #pragma unroll
    for (int k = 0; k < 8; ++k) s[k] += b2f(v[k]);
  }

  __shared__ float sh[16][N_];           // 32 KB
  #pragma unroll
  for (int k = 0; k < 8; ++k) sh[rg][lane * 8 + k] = s[k];
  __syncthreads();

  if (t < N_){
    float acc = 0.f;
    #pragma unroll
    for (int g = 0; g < 16; ++g) acc += sh[g][t];
    sent[((size_t)b * S_ + j) * N_ + t] = acc * inv;
  }
}

// --------------------- K4: aspect head: LN + (256x9) matmul + softmax
__global__ void aspect_k(const float* __restrict__ sent,
                         const float* __restrict__ lns, const float* __restrict__ lnb,
                         const float* __restrict__ Wasp,
                         float* __restrict__ out_adoc, float* __restrict__ aw){
  int sidx = blockIdx.x;   // 0..511
  int t = threadIdx.x;
  float a = sent[(size_t)sidx * N_ + t];        // a-branch = cols [0,256)
  float2 r = block_reduce2(a, a * a);
  float mean = r.x * (1.f / P_);
  float var  = fmaxf(r.y * (1.f / P_) - mean * mean, 0.f);
  float rstd = rsqrtf(var + 1e-5f);
  __shared__ float shv[P_];
  shv[t] = (a - mean) * rstd * lns[t] + lnb[t];
  __syncthreads();
  __shared__ float lg[NASP + 1];
  if (t < NASP + 1){
    float acc = 0.f;
    for (int p = 0; p < P_; ++p) acc += shv[p] * Wasp[p * (NASP + 1) + t];
    lg[t] = acc;
  }
  __syncthreads();
  __shared__ float pr[NASP + 1];
  if (t == 0){
    float m = lg[0];
    #pragma unroll
    for (int i = 1; i < NASP + 1; ++i) m = fmaxf(m, lg[i]);
    float s = 0.f;
    #pragma unroll
    for (int i = 0; i < NASP + 1; ++i){ float e = expf(lg[i] - m); pr[i] = e; s += e; }
    float is = 1.f / s;
    #pragma unroll
    for (int i = 0; i < NASP + 1; ++i) pr[i] *= is;
  }
  __syncthreads();
  if (t < NASP + 1) out_adoc[(size_t)sidx * (NASP + 1) + t] = pr[t];
  if (t < NASP)     aw[(size_t)sidx * NASP + t] = pr[t];
}

// ---------- K5: doc pooling + LN + (256x5) matmul -> result
__global__ void result_k(const float* __restrict__ sent, const float* __restrict__ aw,
                         const float* __restrict__ lns, const float* __restrict__ lnb,
                         const float* __restrict__ Wse, float* __restrict__ out){
  int ba = blockIdx.x;          // b*8 + aspect
  int b = ba >> 3, a = ba & 7;
  int t = threadIdx.x;
  float acc = 0.f, wsum = 0.f;
  for (int s2 = 0; s2 < S_; ++s2){
    float w = aw[((size_t)(b * S_ + s2)) * NASP + a];
    acc  += w * sent[((size_t)(b * S_ + s2)) * N_ + P_ + t];  // s-branch
    wsum += w;
  }
  float d = acc / fmaxf(wsum, 1e-20f);
  float2 r = block_reduce2(d, d * d);
  float mean = r.x * (1.f / P_);
  float var  = fmaxf(r.y * (1.f / P_) - mean * mean, 0.f);
  float rstd = rsqrtf(var + 1e-5f);
  __shared__ float shv[P_];
  shv[t] = (d - mean) * rstd * lns[t] + lnb[t];
  __syncthreads();
  if (t < NRAT){
    float s = 0.f;
    for (int p = 0; p < P_; ++p) s += shv[p] * Wse[p * NRAT + t];
    out[(size_t)ba * NRAT + t] = s;
  }
}

// ---------------------------------------------- K6: echo x -> out (runs last)
__global__ void copy_k(const float4* __restrict__ src, float4* __restrict__ dst){
  size_t i = (size_t)blockIdx.x * 256 + threadIdx.x;
  dst[i] = src[i];
}

// --------------------------------------------------------------------------
extern "C" void kernel_launch(void* const* d_in, const int* in_sizes, int n_in,
                              void* d_out, int out_size, void* d_ws, size_t ws_size,
                              hipStream_t stream) {
  const float* x        = (const float*)d_in[0];
  const int*   p_index  = (const int*)d_in[2];
  const float* ln_a_s   = (const float*)d_in[4];
  const float* ln_a_b   = (const float*)d_in[5];
  const float* W_a      = (const float*)d_in[6];
  const float* ln_s_s   = (const float*)d_in[7];
  const float* ln_s_b   = (const float*)d_in[8];
  const float* W_s      = (const float*)d_in[9];
  const float* ln_asp_s = (const float*)d_in[10];
  const float* ln_asp_b = (const float*)d_in[11];
  const float* W_asp    = (const float*)d_in[12];
  const float* ln_se_s  = (const float*)d_in[13];
  const float* ln_se_b  = (const float*)d_in[14];
  const float* W_se     = (const float*)d_in[15];

  float* out_result = (float*)d_out;                     // 640 f32
  float* out_echo   = out_result + 640;                  // 33.5M f32 (134 MB)
  float* out_adoc   = out_echo + (size_t)M_ * H_;        // 4608 f32

  // Scratch inside the echo region (134 MB): proj 33.5 MB + xhat 67 MB.
  // Echo is written LAST, stream-ordered after every consumer.
  u16* proj = (u16*)out_echo;                            // M_*N_ u16
  u16* xhat = proj + (size_t)M_ * N_;                    // M_*H_ u16

  char* ws = (char*)d_ws;
  u16*   WcT   = (u16*)ws;   ws += (size_t)N_ * H_ * 2;        // 1 MB
  float* biasc = (float*)ws; ws += (size_t)N_ * 4;             // 2 KB
  int*   pi    = (int*)ws;   ws += (size_t)B_ * S_ * 4;        // 2 KB
  float* sent  = (float*)ws; ws += (size_t)B_ * S_ * N_ * 4;   // 1 MB
  float* aw    = (float*)ws; ws += (size_t)B_ * S_ * NASP * 4; // 16 KB

  fold_k<<<N_, 256, 0, stream>>>(W_a, W_s, ln_a_s, ln_a_b, ln_s_s, ln_s_b, WcT, biasc);
  markers_k<<<B_, 64, 0, stream>>>(p_index, pi);
  stats_xhat_k<<<M_, 256, 0, stream>>>(x, xhat);
  gemm_k<<<2048, 256, 0, stream>>>(xhat, WcT, biasc, proj);
  segmean_k<<<dim3(B_, S_), 1024, 0, stream>>>(proj, pi, sent);
  aspect_k<<<B_ * S_, 256, 0, stream>>>(sent, ln_asp_s, ln_asp_b, W_asp, out_adoc, aw);
  result_k<<<B_ * NASP, 256, 0, stream>>>(sent, aw, ln_se_s, ln_se_b, W_se, out_result);
  copy_k<<<(M_ * H_ / 4) / 256, 256, 0, stream>>>((const float4*)x, (float4*)out_echo);
}

// Round 3
// 405.874 us; speedup vs baseline: 1.1842x; 1.0026x over previous
//
#include <hip/hip_runtime.h>
#include <cstdint>
#include <cstddef>

#define B_   16
#define L_   2048
#define H_   1024
#define S_   32
#define P_   256
#define NASP 8
#define NRAT 5
#define M_   (B_*L_)   /* 32768 */
#define N_   (2*P_)    /* 512  */

typedef unsigned short u16;
typedef __bf16 bf16;
typedef u16  u16x4  __attribute__((ext_vector_type(4)));
typedef u16  u16x8  __attribute__((ext_vector_type(8)));
typedef bf16 bf16x8 __attribute__((ext_vector_type(8)));
typedef float f32x4 __attribute__((ext_vector_type(4)));

// f32 -> bf16 bits (round-to-nearest-even), bf16 bits -> f32.
__device__ __forceinline__ u16 f2b(float f){
  unsigned int u = __float_as_uint(f);
  u += 0x7FFFu + ((u >> 16) & 1u);
  return (u16)(u >> 16);
}
__device__ __forceinline__ float b2f(u16 v){
  return __uint_as_float(((unsigned int)v) << 16);
}

// async global->LDS, 16B per lane; LDS dest is wave-uniform base + lane*16.
__device__ __forceinline__ void gload_lds16(const u16* g, u16* l){
  __builtin_amdgcn_global_load_lds(
      (const __attribute__((address_space(1))) unsigned int*)g,
      (__attribute__((address_space(3))) unsigned int*)l, 16, 0, 0);
}

// ---------------------------------------------------------------- utilities
__device__ __forceinline__ float2 block_reduce2(float a, float b){
  __shared__ float sh[8];
  #pragma unroll
  for (int o = 32; o > 0; o >>= 1){
    a += __shfl_down(a, o, 64);
    b += __shfl_down(b, o, 64);
  }
  int w = threadIdx.x >> 6;
  if ((threadIdx.x & 63) == 0){ sh[w] = a; sh[w + 4] = b; }
  __syncthreads();
  float2 r;
  r.x = sh[0] + sh[1] + sh[2] + sh[3];
  r.y = sh[4] + sh[5] + sh[6] + sh[7];
  __syncthreads();
  return r;
}

// ------------------------------------------------- K0a: fold LN into weights
__global__ void fold_k(const float* __restrict__ Wa, const float* __restrict__ Ws,
                       const float* __restrict__ sa, const float* __restrict__ ba,
                       const float* __restrict__ ss, const float* __restrict__ bs,
                       u16* __restrict__ WcT, float* __restrict__ biasc){
  int n = blockIdx.x;                 // 0..511
  const float* W; const float* sc; const float* bi; int col;
  if (n < P_){ W = Wa; sc = sa; bi = ba; col = n; }
  else       { W = Ws; sc = ss; bi = bs; col = n - P_; }
  float bacc = 0.f;
  #pragma unroll
  for (int i = 0; i < 4; ++i){
    int k = threadIdx.x + i * 256;
    float w = W[(size_t)k * P_ + col];
    WcT[(size_t)n * H_ + k] = f2b(w * sc[k]);
    bacc += w * bi[k];
  }
  float2 r = block_reduce2(bacc, 0.f);
  if (threadIdx.x == 0) biasc[n] = r.x;
}

// --------------------------------------------- K0b: sentence marker indices
__global__ void markers_k(const int* __restrict__ p_index, int* __restrict__ pi){
  int b = blockIdx.x;
  int lane = threadIdx.x;             // 64 threads = 1 wave
  int cnt = 0;
  for (int c = 0; c < L_ / 64; ++c){
    int pos = c * 64 + lane;
    bool f = p_index[(size_t)b * L_ + pos] > 0;
    unsigned long long m = __ballot(f);
    int before = __popcll(m & ((1ull << lane) - 1ull));
    if (f){
      int idx = cnt + before;
      if (idx < S_) pi[b * S_ + idx] = pos;
    }
    cnt += __popcll(m);
  }
}

// -------------------- K1: fused per-row LN stats + normalize -> bf16 xhat
__global__ void stats_xhat_k(const float* __restrict__ x, u16* __restrict__ xhat){
  int row = blockIdx.x;
  int t = threadIdx.x;
  float4 v = ((const float4*)(x + (size_t)row * H_))[t];
  float s  = v.x + v.y + v.z + v.w;
  float ss = v.x*v.x + v.y*v.y + v.z*v.z + v.w*v.w;
  float2 r = block_reduce2(s, ss);
  float mean = r.x * (1.f / H_);
  float var  = fmaxf(r.y * (1.f / H_) - mean * mean, 0.f);
  float rstd = rsqrtf(var + 1e-5f);
  u16x4 o;
  o[0] = f2b((v.x - mean) * rstd);
  o[1] = f2b((v.y - mean) * rstd);
  o[2] = f2b((v.z - mean) * rstd);
  o[3] = f2b((v.w - mean) * rstd);
  ((u16x4*)(xhat + (size_t)row * H_))[t] = o;
}

// --------------------------- K2: GEMM (bf16 A from xhat) + bias + GELU
// m97-structure: 128x128 tile, BK=32, 4 waves (2x2), 4x4 16x16x32 MFMA per
// wave, global_load_lds width-16 staging into LINEAR LDS, both-sides k-chunk
// XOR swizzle (chunk ^= (row>>1)&3) so ds_read_b128 is bank-conflict-free
// (rule #21: linear dest + inverse-swizzled SOURCE + swizzled READ).
// XCD swizzle: the 4 n-tiles of one m-tile are adjacent on one XCD -> A-tile
// L2-resident (A-tile 256KB << 4MB L2/XCD).
__global__ __launch_bounds__(256) void gemm_k(const u16* __restrict__ xhat,
                                              const u16* __restrict__ WcT,
                                              const float* __restrict__ biasc,
                                              u16* __restrict__ proj){
  __shared__ __align__(16) u16 As[128 * 32];   // 8 KB, linear [row][k] 64B rows
  __shared__ __align__(16) u16 Bs[128 * 32];   // 8 KB
  int t = threadIdx.x;
  unsigned int l = blockIdx.x;          // 0..1023
  unsigned int xcd  = l & 7;
  unsigned int slot = l >> 3;           // 0..127
  int nbase = (int)(slot & 3) * 128;
  int mbase = (int)(xcd * 32 + (slot >> 2)) * 128;

  int w = t >> 6, lane = t & 63;
  int wr = w >> 1, wc = w & 1;
  int quad = lane >> 4, l15 = lane & 15;

  // Staging: instr j = w*2+i covers rows j*16..j*16+15 (16 rows x 64B = 1KB).
  // lane -> row j*16 + (lane>>2), dest chunk lane&3 (linear), source chunk
  // g = (lane&3) ^ ((lane>>3)&3)  [= (lane&3) ^ ((row>>1)&3)].
  int g = (lane & 3) ^ ((lane >> 3) & 3);
  int r0 = (w * 2 + 0) * 16 + (lane >> 2);
  int r1 = (w * 2 + 1) * 16 + (lane >> 2);
  const u16* gA0 = xhat + (size_t)(mbase + r0) * H_ + g * 8;
  const u16* gA1 = xhat + (size_t)(mbase + r1) * H_ + g * 8;
  const u16* gB0 = WcT  + (size_t)(nbase + r0) * H_ + g * 8;
  const u16* gB1 = WcT  + (size_t)(nbase + r1) * H_ + g * 8;
  u16* lA0 = As + (w * 2 + 0) * 512;    // 1KB = 512 u16 per instr
  u16* lA1 = As + (w * 2 + 1) * 512;
  u16* lB0 = Bs + (w * 2 + 0) * 512;
  u16* lB1 = Bs + (w * 2 + 1) * 512;

  f32x4 acc[4][4] = {};

  for (int kk = 0; kk < H_; kk += 32){
    __syncthreads();
    gload_lds16(gA0 + kk, lA0);
    gload_lds16(gA1 + kk, lA1);
    gload_lds16(gB0 + kk, lB0);
    gload_lds16(gB1 + kk, lB1);
    __syncthreads();   // compiler drains vmcnt before barrier

    bf16x8 af[4], bfr[4];
    #pragma unroll
    for (int im = 0; im < 4; ++im){
      int R = wr * 64 + im * 16 + l15;
      int cq = quad ^ ((R >> 1) & 3);
      af[im] = *reinterpret_cast<const bf16x8*>(&As[R * 32 + cq * 8]);
    }
    #pragma unroll
    for (int in = 0; in < 4; ++in){
      int R = wc * 64 + in * 16 + l15;
      int cq = quad ^ ((R >> 1) & 3);
      bfr[in] = *reinterpret_cast<const bf16x8*>(&Bs[R * 32 + cq * 8]);
    }
    #pragma unroll
    for (int im = 0; im < 4; ++im)
      #pragma unroll
      for (int in = 0; in < 4; ++in)
        acc[im][in] = __builtin_amdgcn_mfma_f32_16x16x32_bf16(af[im], bfr[in], acc[im][in], 0, 0, 0);
  }

  // epilogue: bias + exact gelu + bf16 store
  #pragma unroll
  for (int in = 0; in < 4; ++in){
    int col = nbase + wc * 64 + in * 16 + l15;
    float bv = biasc[col];
    #pragma unroll
    for (int im = 0; im < 4; ++im){
      #pragma unroll
      for (int r = 0; r < 4; ++r){
        int rowg = mbase + wr * 64 + im * 16 + quad * 4 + r;
        float vv = acc[im][in][r] + bv;
        float gl = 0.5f * vv * (1.0f + erff(vv * 0.70710678118654752f));
        proj[(size_t)rowg * N_ + col] = f2b(gl);
      }
    }
  }
}

// ------------------------------------------------- K3: segment (span) means
// 1024 threads = 16 waves per block; each wave reads one FULL 1KB row
// (64 lanes x 16B), 16 rows in flight per iteration. 512 blocks x 1024 thr
// = exactly 2 blocks/CU = 32 waves/CU. Cross-wave reduce through 32KB LDS.
__global__ __launch_bounds__(1024) void segmean_k(const u16* __restrict__ proj,
                                                  const int* __restrict__ pi,
                                                  float* __restrict__ sent){
  int b = blockIdx.x, j = blockIdx.y;
  int t = threadIdx.x;
  int rg   = t >> 6;        // 0..15 (wave id = row group)
  int lane = t & 63;        // lane covers cols [lane*8, lane*8+8)
  int end   = pi[b * S_ + j];
  int start = (j == 0) ? 0 : (pi[b * S_ + j - 1] + 1);
  end   = min(max(end, 0), L_);
  start = min(max(start, 0), end);
  int cnt = max(end - start, 1);
  float inv = 1.0f / (float)cnt;

  float s[8] = {};
  const u16* base = proj + ((size_t)b * L_ + start) * N_ + lane * 8;
  for (int r = rg; r < cnt; r += 16){
    u16x8 v = *reinterpret_cast<const u16x8*>(base + (size_t)r * N_);
    #pragma unroll
    for (int k = 0; k < 8; ++k) s[k] += b2f(v[k]);
  }

  __shared__ float sh[16][N_];           // 32 KB
  #pragma unroll
  for (int k = 0; k < 8; ++k) sh[rg][lane * 8 + k] = s[k];
  __syncthreads();

  if (t < N_){
    float acc = 0.f;
    #pragma unroll
    for (int g = 0; g < 16; ++g) acc += sh[g][t];
    sent[((size_t)b * S_ + j) * N_ + t] = acc * inv;
  }
}

// --------------------- K4: aspect head: LN + (256x9) matmul + softmax
__global__ void aspect_k(const float* __restrict__ sent,
                         const float* __restrict__ lns, const float* __restrict__ lnb,
                         const float* __restrict__ Wasp,
                         float* __restrict__ out_adoc, float* __restrict__ aw){
  int sidx = blockIdx.x;   // 0..511
  int t = threadIdx.x;
  float a = sent[(size_t)sidx * N_ + t];        // a-branch = cols [0,256)
  float2 r = block_reduce2(a, a * a);
  float mean = r.x * (1.f / P_);
  float var  = fmaxf(r.y * (1.f / P_) - mean * mean, 0.f);
  float rstd = rsqrtf(var + 1e-5f);
  __shared__ float shv[P_];
  shv[t] = (a - mean) * rstd * lns[t] + lnb[t];
  __syncthreads();
  __shared__ float lg[NASP + 1];
  if (t < NASP + 1){
    float acc = 0.f;
    for (int p = 0; p < P_; ++p) acc += shv[p] * Wasp[p * (NASP + 1) + t];
    lg[t] = acc;
  }
  __syncthreads();
  __shared__ float pr[NASP + 1];
  if (t == 0){
    float m = lg[0];
    #pragma unroll
    for (int i = 1; i < NASP + 1; ++i) m = fmaxf(m, lg[i]);
    float s = 0.f;
    #pragma unroll
    for (int i = 0; i < NASP + 1; ++i){ float e = expf(lg[i] - m); pr[i] = e; s += e; }
    float is = 1.f / s;
    #pragma unroll
    for (int i = 0; i < NASP + 1; ++i) pr[i] *= is;
  }
  __syncthreads();
  if (t < NASP + 1) out_adoc[(size_t)sidx * (NASP + 1) + t] = pr[t];
  if (t < NASP)     aw[(size_t)sidx * NASP + t] = pr[t];
}

// ---------- K5: doc pooling + LN + (256x5) matmul -> result
__global__ void result_k(const float* __restrict__ sent, const float* __restrict__ aw,
                         const float* __restrict__ lns, const float* __restrict__ lnb,
                         const float* __restrict__ Wse, float* __restrict__ out){
  int ba = blockIdx.x;          // b*8 + aspect
  int b = ba >> 3, a = ba & 7;
  int t = threadIdx.x;
  float acc = 0.f, wsum = 0.f;
  for (int s2 = 0; s2 < S_; ++s2){
    float w = aw[((size_t)(b * S_ + s2)) * NASP + a];
    acc  += w * sent[((size_t)(b * S_ + s2)) * N_ + P_ + t];  // s-branch
    wsum += w;
  }
  float d = acc / fmaxf(wsum, 1e-20f);
  float2 r = block_reduce2(d, d * d);
  float mean = r.x * (1.f / P_);
  float var  = fmaxf(r.y * (1.f / P_) - mean * mean, 0.f);
  float rstd = rsqrtf(var + 1e-5f);
  __shared__ float shv[P_];
  shv[t] = (d - mean) * rstd * lns[t] + lnb[t];
  __syncthreads();
  if (t < NRAT){
    float s = 0.f;
    for (int p = 0; p < P_; ++p) s += shv[p] * Wse[p * NRAT + t];
    out[(size_t)ba * NRAT + t] = s;
  }
}

// ---------------------------------------------- K6: echo x -> out (runs last)
__global__ void copy_k(const float4* __restrict__ src, float4* __restrict__ dst){
  size_t i = (size_t)blockIdx.x * 256 + threadIdx.x;
  dst[i] = src[i];
}

// --------------------------------------------------------------------------
extern "C" void kernel_launch(void* const* d_in, const int* in_sizes, int n_in,
                              void* d_out, int out_size, void* d_ws, size_t ws_size,
                              hipStream_t stream) {
  const float* x        = (const float*)d_in[0];
  const int*   p_index  = (const int*)d_in[2];
  const float* ln_a_s   = (const float*)d_in[4];
  const float* ln_a_b   = (const float*)d_in[5];
  const float* W_a      = (const float*)d_in[6];
  const float* ln_s_s   = (const float*)d_in[7];
  const float* ln_s_b   = (const float*)d_in[8];
  const float* W_s      = (const float*)d_in[9];
  const float* ln_asp_s = (const float*)d_in[10];
  const float* ln_asp_b = (const float*)d_in[11];
  const float* W_asp    = (const float*)d_in[12];
  const float* ln_se_s  = (const float*)d_in[13];
  const float* ln_se_b  = (const float*)d_in[14];
  const float* W_se     = (const float*)d_in[15];

  float* out_result = (float*)d_out;                     // 640 f32
  float* out_echo   = out_result + 640;                  // 33.5M f32 (134 MB)
  float* out_adoc   = out_echo + (size_t)M_ * H_;        // 4608 f32

  // Scratch inside the echo region (134 MB): proj 33.5 MB + xhat 67 MB.
  // Echo is written LAST, stream-ordered after every consumer.
  u16* proj = (u16*)out_echo;                            // M_*N_ u16
  u16* xhat = proj + (size_t)M_ * N_;                    // M_*H_ u16

  char* ws = (char*)d_ws;
  u16*   WcT   = (u16*)ws;   ws += (size_t)N_ * H_ * 2;        // 1 MB
  float* biasc = (float*)ws; ws += (size_t)N_ * 4;             // 2 KB
  int*   pi    = (int*)ws;   ws += (size_t)B_ * S_ * 4;        // 2 KB
  float* sent  = (float*)ws; ws += (size_t)B_ * S_ * N_ * 4;   // 1 MB
  float* aw    = (float*)ws; ws += (size_t)B_ * S_ * NASP * 4; // 16 KB

  fold_k<<<N_, 256, 0, stream>>>(W_a, W_s, ln_a_s, ln_a_b, ln_s_s, ln_s_b, WcT, biasc);
  markers_k<<<B_, 64, 0, stream>>>(p_index, pi);
  stats_xhat_k<<<M_, 256, 0, stream>>>(x, xhat);
  gemm_k<<<1024, 256, 0, stream>>>(xhat, WcT, biasc, proj);
  segmean_k<<<dim3(B_, S_), 1024, 0, stream>>>(proj, pi, sent);
  aspect_k<<<B_ * S_, 256, 0, stream>>>(sent, ln_asp_s, ln_asp_b, W_asp, out_adoc, aw);
  result_k<<<B_ * NASP, 256, 0, stream>>>(sent, aw, ln_se_s, ln_se_b, W_se, out_result);
  copy_k<<<(M_ * H_ / 4) / 256, 256, 0, stream>>>((const float4*)x, (float4*)out_echo);
}